// Round 1
// baseline (334.423 us; speedup 1.0000x reference)
//
#include <hip/hip_runtime.h>

// Problem constants (match reference)
#define BB 2
#define CC 64
#define HH 512
#define WW 512
#define NN 4096
#define KK 5
#define HWp (HH * WW)

__global__ void zero_out_kernel(float* out) { out[0] = 0.0f; }

__global__ __launch_bounds__(256) void feature_loss_kernel(
    const float* __restrict__ inputs_ref,
    const float* __restrict__ inputs_other,
    const float* __restrict__ weights,
    const int*   __restrict__ inds_ref,
    const int*   __restrict__ inds_other,
    const int*   __restrict__ rand_inds,
    float*       __restrict__ out)
{
    const int tid  = threadIdx.x;
    const int lane = tid & 63;          // channel index (C == 64 == wave size)
    const int wave = tid >> 6;          // 4 waves per block, one point each

    const int gidx = blockIdx.x * 4 + wave;   // global point index in [0, B*N)
    if (gidx >= BB * NN) return;
    const int b = gidx / NN;
    const int i = gidx - b * NN;

    // ---- wave-uniform index math ----
    const int* ir = inds_ref  + b * 2 * NN;   // ir[i]=x, ir[NN+i]=y
    const int* io = inds_other + b * 2 * NN;
    const int xr = ir[i];
    const int yr = ir[NN + i];
    const int lin_r = HH * yr + xr;                 // H*y + x
    const int lin_o = HH * io[NN + i] + io[i];

    const int* rj = rand_inds + ((long long)b * NN + i) * KK;
    int   linj[KK];
    float dist[KK];
#pragma unroll
    for (int k = 0; k < KK; ++k) {
        const int j = rj[k];
        linj[k] = HH * io[NN + j] + io[j];
        const float dx = (float)(xr - ir[j]);
        const float dy = (float)(yr - ir[NN + j]);
        dist[k] = sqrtf(dx * dx + dy * dy);
    }

    // ---- strided feature gathers: lane c loads channel c (stride H*W) ----
    const long long cbase = (long long)b * CC * HWp + (long long)lane * HWp;
    const float* rbase = inputs_ref  + cbase;
    const float* obase = inputs_other + cbase;

    const float fr = rbase[lin_r];
    const float fo = obase[lin_o];
    float fmm[KK];
#pragma unroll
    for (int k = 0; k < KK; ++k) fmm[k] = obase[linj[k]];

    float s[1 + KK];
    {
        const float dm = fr - fo;
        s[0] = dm * dm;
    }
#pragma unroll
    for (int k = 0; k < KK; ++k) {
        const float t = fr - fmm[k];
        s[1 + k] = t * t;
    }

    // ---- wave-wide (64-lane) sum reductions for the 6 squared distances ----
#pragma unroll
    for (int r = 0; r < 1 + KK; ++r) {
        float v = s[r];
#pragma unroll
        for (int off = 32; off > 0; off >>= 1)
            v += __shfl_xor(v, off, 64);
        s[r] = v;
    }

    if (lane == 0) {
        const float max_distance = 724.07734f;          // sqrt(512^2 + 512^2)
        const float thr_nomatch  = 16.0f;               // 0.5^2 * C
        float loss_match = fmaxf(s[0], 0.0f);           // FEAT_THRESH_MATCH = 0
        float acc = weights[b * NN + i] * loss_match;
#pragma unroll
        for (int k = 0; k < KK; ++k) {
            const float lmm  = fminf(s[1 + k], thr_nomatch);
            // w_mm = -NON_MATCH_WEIGHT * d / max_distance / K, with weight==K==5
            const float w_mm = -dist[k] / max_distance;
            acc += w_mm * lmm;
        }
        acc *= (1.0f / (float)((KK + 1) * NN));         // size_average
        atomicAdd(out, acc);
    }
}

extern "C" void kernel_launch(void* const* d_in, const int* in_sizes, int n_in,
                              void* d_out, int out_size, void* d_ws, size_t ws_size,
                              hipStream_t stream) {
    const float* inputs_ref   = (const float*)d_in[0];
    const float* inputs_other = (const float*)d_in[1];
    const float* weights      = (const float*)d_in[2];
    const int*   inds_ref     = (const int*)d_in[3];
    const int*   inds_other   = (const int*)d_in[4];
    const int*   rand_inds    = (const int*)d_in[5];
    float* out = (float*)d_out;

    // d_out is re-poisoned (0xAA) before every timed replay: zero it first.
    zero_out_kernel<<<1, 1, 0, stream>>>(out);

    const int points = BB * NN;                 // 8192 waves, 4 per block
    const int blocks = (points + 3) / 4;        // 2048 blocks of 256 threads
    feature_loss_kernel<<<blocks, 256, 0, stream>>>(
        inputs_ref, inputs_other, weights, inds_ref, inds_other, rand_inds, out);
}

// Round 2
// 278.102 us; speedup vs baseline: 1.2025x; 1.2025x over previous
//
#include <hip/hip_runtime.h>

// Problem constants (match reference)
#define BB 2
#define CC 64
#define HH 512
#define WW 512
#define NN 4096
#define KK 5
#define HWp (HH * WW)

__global__ void zero_out_kernel(float* out) { out[0] = 0.0f; }

// ---------------------------------------------------------------------------
// Pass 1: gather the N sampled feature vectors of ref and other into compact
// [B][N][C] buffers. lane = point (random low address bits -> spreads requests
// across HBM channels / L2 banks; the old lane=channel layout put all 64 lanes
// 1 MiB apart = same channel+set = full serialization).
// wave = (sel, b, c, g): sel 0=ref 1=other, c = channel, g = 64-point group.
// ---------------------------------------------------------------------------
__global__ __launch_bounds__(256) void gather_kernel(
    const float* __restrict__ inputs_ref,
    const float* __restrict__ inputs_other,
    const int*   __restrict__ inds_ref,
    const int*   __restrict__ inds_other,
    float*       __restrict__ Fr,      // [B][N][C]
    float*       __restrict__ Fo)      // [B][N][C]
{
    const int lane = threadIdx.x & 63;
    int w = (blockIdx.x * 256 + threadIdx.x) >> 6;
    const int g = w & 63;  w >>= 6;        // N/64 = 64 point-groups
    const int c = w & 63;  w >>= 6;        // C = 64 channels
    const int b = w & 1;   w >>= 1;        // B = 2
    const int sel = w;                     // 0 = ref, 1 = other

    const int i = g * 64 + lane;
    const int* ind = (sel ? inds_other : inds_ref) + b * 2 * NN;
    const int lin = HH * ind[NN + i] + ind[i];         // H*y + x

    const float* src = (sel ? inputs_other : inputs_ref)
                       + (size_t)(b * CC + c) * HWp;
    float* dst = sel ? Fo : Fr;
    // scattered 4B write, stride 256B across lanes -> absorbed by L2 (4MB buf)
    dst[(size_t)(b * NN + i) * CC + c] = src[lin];
}

// ---------------------------------------------------------------------------
// Pass 2: one wave per match point, lane = channel. All 7 feature vectors are
// contiguous 256 B reads from the compact L2-resident buffers (the 5 mismatch
// vectors are re-gathers of Fo at partner points j = rand_inds[i][k]).
// ---------------------------------------------------------------------------
__global__ __launch_bounds__(256) void loss_kernel(
    const float* __restrict__ Fr,
    const float* __restrict__ Fo,
    const float* __restrict__ weights,
    const int*   __restrict__ inds_ref,
    const int*   __restrict__ rand_inds,
    float*       __restrict__ out)
{
    const int tid  = threadIdx.x;
    const int lane = tid & 63;
    const int wave = tid >> 6;                 // 4 waves / block
    const int gidx = blockIdx.x * 4 + wave;    // point index in [0, B*N)
    const int b = gidx / NN;
    const int i = gidx - b * NN;

    const int* ir = inds_ref + b * 2 * NN;     // x at [i], y at [NN+i]
    const int xr = ir[i];
    const int yr = ir[NN + i];
    const int* rj = rand_inds + (size_t)(b * NN + i) * KK;

    const float fr = Fr[(size_t)(b * NN + i) * CC + lane];
    const float fo = Fo[(size_t)(b * NN + i) * CC + lane];

    float s[1 + KK];
    float dist[KK];
    { const float d = fr - fo; s[0] = d * d; }
#pragma unroll
    for (int k = 0; k < KK; ++k) {
        const int j = rj[k];                               // wave-uniform
        const float fm = Fo[(size_t)(b * NN + j) * CC + lane];
        const float t = fr - fm;
        s[1 + k] = t * t;
        const float dx = (float)(xr - ir[j]);
        const float dy = (float)(yr - ir[NN + j]);
        dist[k] = sqrtf(dx * dx + dy * dy);
    }

    // 64-lane sum reductions for the 6 squared feature distances
#pragma unroll
    for (int r = 0; r < 1 + KK; ++r) {
        float v = s[r];
#pragma unroll
        for (int off = 32; off > 0; off >>= 1)
            v += __shfl_xor(v, off, 64);
        s[r] = v;
    }

    __shared__ float part[4];
    if (lane == 0) {
        const float max_distance = 724.07734f;   // sqrt(512^2+512^2)
        const float thr_nomatch  = 16.0f;        // 0.5^2 * C
        float acc = weights[b * NN + i] * fmaxf(s[0], 0.0f);
#pragma unroll
        for (int k = 0; k < KK; ++k) {
            // w_mm = -NON_MATCH_WEIGHT * d / max_dist / K, weight==K==5
            acc += (-dist[k] / max_distance) * fminf(s[1 + k], thr_nomatch);
        }
        part[wave] = acc * (1.0f / (float)((KK + 1) * NN));
    }
    __syncthreads();
    if (tid == 0) {
        float t = part[0] + part[1] + part[2] + part[3];
        atomicAdd(out, t);                        // 2048 atomics total
    }
}

extern "C" void kernel_launch(void* const* d_in, const int* in_sizes, int n_in,
                              void* d_out, int out_size, void* d_ws, size_t ws_size,
                              hipStream_t stream) {
    const float* inputs_ref   = (const float*)d_in[0];
    const float* inputs_other = (const float*)d_in[1];
    const float* weights      = (const float*)d_in[2];
    const int*   inds_ref     = (const int*)d_in[3];
    const int*   inds_other   = (const int*)d_in[4];
    const int*   rand_inds    = (const int*)d_in[5];
    float* out = (float*)d_out;

    // workspace: Fr [B][N][C] then Fo [B][N][C]  (2 MB each)
    float* Fr = (float*)d_ws;
    float* Fo = Fr + (size_t)BB * NN * CC;

    zero_out_kernel<<<1, 1, 0, stream>>>(out);

    // pass 1: 2(sel) * B * C * (N/64) = 16384 waves -> 4096 blocks of 256
    gather_kernel<<<4096, 256, 0, stream>>>(
        inputs_ref, inputs_other, inds_ref, inds_other, Fr, Fo);

    // pass 2: B*N = 8192 waves -> 2048 blocks of 256
    loss_kernel<<<2048, 256, 0, stream>>>(
        Fr, Fo, weights, inds_ref, rand_inds, out);
}

// Round 3
// 259.679 us; speedup vs baseline: 1.2878x; 1.0709x over previous
//
#include <hip/hip_runtime.h>

// Problem constants (match reference)
#define BB 2
#define CC 64
#define HH 512
#define WW 512
#define NN 4096
#define KK 5
#define HWp (HH * WW)

// ---------------------------------------------------------------------------
// Pass 1: gather sampled feature vectors into compact [B][N][C] buffers.
// wave = (sel, b, point-group g, channel-chunk of 16). lane = point.
//  - 16 independent strided gathers per lane in flight (latency hiding)
//  - lane's 16 results are contiguous in dst -> four float4 stores to ONE
//    64 B line (coalesced, 4x fewer store requests than scalar)
//  - lane addresses within one load instr have random low bits (lin index)
//    -> requests spread across HBM channels / L2 banks (round-1 fix kept)
// 1024 waves = 256 blocks of 256 threads.
// ---------------------------------------------------------------------------
__global__ __launch_bounds__(256) void gather_kernel(
    const float* __restrict__ inputs_ref,
    const float* __restrict__ inputs_other,
    const int*   __restrict__ inds_ref,
    const int*   __restrict__ inds_other,
    float*       __restrict__ Fr,      // [B][N][C]
    float*       __restrict__ Fo)      // [B][N][C]
{
    const int lane = threadIdx.x & 63;
    int w = (blockIdx.x * 256 + threadIdx.x) >> 6;   // wave id, 0..1023
    const int chunk = w & 3;  w >>= 2;   // 4 chunks of 16 channels
    const int g     = w & 63; w >>= 6;   // N/64 = 64 point groups
    const int b     = w & 1;  w >>= 1;   // B = 2
    const int sel   = w;                 // 0 = ref, 1 = other

    const int i = g * 64 + lane;
    const int* ind = (sel ? inds_other : inds_ref) + b * 2 * NN;
    const int lin = HH * ind[NN + i] + ind[i];       // H*y + x

    const float* src = (sel ? inputs_other : inputs_ref)
                       + (size_t)b * CC * HWp
                       + (size_t)chunk * 16 * HWp
                       + lin;
    float v[16];
#pragma unroll
    for (int cc = 0; cc < 16; ++cc)
        v[cc] = src[(size_t)cc * HWp];               // 16 independent gathers

    float* dst = (sel ? Fo : Fr) + (size_t)(b * NN + i) * CC + chunk * 16;
#pragma unroll
    for (int q = 0; q < 4; ++q)
        ((float4*)dst)[q] = make_float4(v[4*q], v[4*q+1], v[4*q+2], v[4*q+3]);
}

// ---------------------------------------------------------------------------
// Pass 2: one wave per match point, lane = channel. All 7 feature vectors are
// contiguous 256 B reads from the compact L2-resident buffers. Per-block
// partial sum written to ws (no global atomics).
// ---------------------------------------------------------------------------
__global__ __launch_bounds__(256) void loss_kernel(
    const float* __restrict__ Fr,
    const float* __restrict__ Fo,
    const float* __restrict__ weights,
    const int*   __restrict__ inds_ref,
    const int*   __restrict__ rand_inds,
    float*       __restrict__ partials)  // [gridDim.x]
{
    const int tid  = threadIdx.x;
    const int lane = tid & 63;
    const int wave = tid >> 6;                 // 4 waves / block
    const int gidx = blockIdx.x * 4 + wave;    // point index in [0, B*N)
    const int b = gidx / NN;
    const int i = gidx - b * NN;

    const int* ir = inds_ref + b * 2 * NN;     // x at [i], y at [NN+i]
    const int xr = ir[i];
    const int yr = ir[NN + i];
    const int* rj = rand_inds + (size_t)(b * NN + i) * KK;

    const float fr = Fr[(size_t)(b * NN + i) * CC + lane];
    const float fo = Fo[(size_t)(b * NN + i) * CC + lane];

    float s[1 + KK];
    float dist[KK];
    { const float d = fr - fo; s[0] = d * d; }
#pragma unroll
    for (int k = 0; k < KK; ++k) {
        const int j = rj[k];                               // wave-uniform
        const float fm = Fo[(size_t)(b * NN + j) * CC + lane];
        const float t = fr - fm;
        s[1 + k] = t * t;
        const float dx = (float)(xr - ir[j]);
        const float dy = (float)(yr - ir[NN + j]);
        dist[k] = sqrtf(dx * dx + dy * dy);
    }

    // 64-lane sum reductions for the 6 squared feature distances
#pragma unroll
    for (int r = 0; r < 1 + KK; ++r) {
        float v = s[r];
#pragma unroll
        for (int off = 32; off > 0; off >>= 1)
            v += __shfl_xor(v, off, 64);
        s[r] = v;
    }

    __shared__ float part[4];
    if (lane == 0) {
        const float max_distance = 724.07734f;   // sqrt(512^2+512^2)
        const float thr_nomatch  = 16.0f;        // 0.5^2 * C
        float acc = weights[b * NN + i] * fmaxf(s[0], 0.0f);
#pragma unroll
        for (int k = 0; k < KK; ++k) {
            // w_mm = -NON_MATCH_WEIGHT * d / max_dist / K, weight==K==5
            acc += (-dist[k] / max_distance) * fminf(s[1 + k], thr_nomatch);
        }
        part[wave] = acc * (1.0f / (float)((KK + 1) * NN));
    }
    __syncthreads();
    if (tid == 0)
        partials[blockIdx.x] = part[0] + part[1] + part[2] + part[3];
}

// ---------------------------------------------------------------------------
// Final: one block reduces the 2048 per-block partials and writes out[0].
// ---------------------------------------------------------------------------
__global__ __launch_bounds__(256) void reduce_kernel(
    const float* __restrict__ partials, int n, float* __restrict__ out)
{
    const int tid = threadIdx.x;
    float v = 0.0f;
    for (int idx = tid; idx < n; idx += 256)
        v += partials[idx];
#pragma unroll
    for (int off = 32; off > 0; off >>= 1)
        v += __shfl_xor(v, off, 64);
    __shared__ float part[4];
    if ((tid & 63) == 0) part[tid >> 6] = v;
    __syncthreads();
    if (tid == 0)
        out[0] = part[0] + part[1] + part[2] + part[3];
}

extern "C" void kernel_launch(void* const* d_in, const int* in_sizes, int n_in,
                              void* d_out, int out_size, void* d_ws, size_t ws_size,
                              hipStream_t stream) {
    const float* inputs_ref   = (const float*)d_in[0];
    const float* inputs_other = (const float*)d_in[1];
    const float* weights      = (const float*)d_in[2];
    const int*   inds_ref     = (const int*)d_in[3];
    const int*   inds_other   = (const int*)d_in[4];
    const int*   rand_inds    = (const int*)d_in[5];
    float* out = (float*)d_out;

    // workspace layout: Fr [B][N][C], Fo [B][N][C] (2 MB each), partials 8 KB
    float* Fr = (float*)d_ws;
    float* Fo = Fr + (size_t)BB * NN * CC;
    float* partials = Fo + (size_t)BB * NN * CC;

    // pass 1: 2(sel)*2(b)*64(g)*4(chunk) = 1024 waves -> 256 blocks
    gather_kernel<<<256, 256, 0, stream>>>(
        inputs_ref, inputs_other, inds_ref, inds_other, Fr, Fo);

    // pass 2: B*N = 8192 waves -> 2048 blocks, per-block partials
    loss_kernel<<<2048, 256, 0, stream>>>(
        Fr, Fo, weights, inds_ref, rand_inds, partials);

    // pass 3: single-block tree reduction -> out[0] (overwrites poison)
    reduce_kernel<<<1, 256, 0, stream>>>(partials, 2048, out);
}